// Round 2
// baseline (6586.990 us; speedup 1.0000x reference)
//
#include <hip/hip_runtime.h>
#include <hip/hip_fp16.h>

// LSTMPredictor: B=32, T=512, H=128, L=5, IN=1, OUT=16, future=18 -> 3 autoregressive iters.
// Key transform: the 3 reference iterations share the full prefix -> ONE 514-step scan with
// carried (h,c); FC head at t=511,512,513; feedback x[512]=out0[:,15], x[513]=out1[:,15].
//
// 160 persistent WGs = 32 batch x 5 layers, pipelined with 1-slot skew per layer.
// W_hh fp32 in VGPRs (recurrent path exact), W_ih f16-packed in VGPRs (feedforward only).
// Cross-WG handoff: agent-scope atomics on a 16-deep h ring + monotonic flags in d_ws.
//
// R1 fix: ALL layers publish their progress flag (r0 bug: l==4 never published ->
// layer-3 backpressure spun its guard loop every step -> multi-minute run -> harness timeout).
// R1 opt: upstream-h spin moved AFTER the recurrent matvec (overlaps ~1024 cyc of FMA).

#define RING 16
#define FLAGL_OFF   0                 // int flagL[32][5], stride 64 ints
#define FCFLAG_OFF  (64*1024)         // int fcflag[32], stride 64 ints
#define FCOUT_OFF   (128*1024)        // float fcout[32][2]
#define RING_OFF    (256*1024)        // float ring[32][4][RING][128]  (1 MB)
#define WHHT_OFF    (2*1024*1024)     // float WhhT[5][128][512]       (1.25 MB)
#define WIHPK_OFF   (4*1024*1024)     // __half2 WihPkT[4][64][512]    (0.5 MB)

#define AGENT __HIP_MEMORY_SCOPE_AGENT

__device__ __forceinline__ float sigm(float x)   { return 1.f / (1.f + __expf(-x)); }
__device__ __forceinline__ float tanh_f(float x) { return 2.f / (1.f + __expf(-2.f * x)) - 1.f; }

// ---------------- init: zero flags, transpose W_hh, transpose+f16-pack W_ih_rest ----------
__global__ void lstm_init(const float* __restrict__ WihR, const float* __restrict__ Whh,
                          char* __restrict__ ws)
{
    int idx = blockIdx.x * blockDim.x + threadIdx.x;
    int stride = gridDim.x * blockDim.x;

    int* wsi = (int*)ws;                       // zero [0, 256KB): flags + fcout
    for (int i = idx; i < 65536; i += stride) wsi[i] = 0;

    float* WhhT = (float*)(ws + WHHT_OFF);     // WhhT[(l*128+k)*512+row] = Whh[l][row][k]
    for (int i = idx; i < 5*128*512; i += stride) {
        int row = i & 511, k = (i >> 9) & 127, l = i >> 16;
        WhhT[i] = Whh[(l*512 + row)*128 + k];
    }

    __half2* WP = (__half2*)(ws + WIHPK_OFF);  // WP[(li*64+m)*512+row] = pack(Wih[li][row][2m],[2m+1])
    for (int i = idx; i < 4*64*512; i += stride) {
        int row = i & 511, m = (i >> 9) & 63, li = i >> 15;
        const float* s = &WihR[(li*512 + row)*128 + 2*m];
        WP[i] = __floats2half2_rn(s[0], s[1]);
    }
}

// ---------------- main persistent pipeline kernel ----------------
__global__ void __launch_bounds__(512, 2)
lstm_main(const float* __restrict__ x_in, const float* __restrict__ Wih0,
          const float* __restrict__ bih,  const float* __restrict__ bhh,
          const float* __restrict__ W1,   const float* __restrict__ b1,
          const float* __restrict__ W2,   const float* __restrict__ b2,
          float* __restrict__ out, char* __restrict__ ws)
{
    __shared__ float4 part4[512];     // per-(g,r) gate partials (i,f,g,o)
    __shared__ float hown[128];       // this layer's h(t-1) broadcast buffer
    __shared__ float hin[128];        // upstream h(t) broadcast buffer
    __shared__ float zbs[128];        // FC: relu(h)
    __shared__ float z2s[128];        // FC: relu(z@W1+b1)

    const int tid = threadIdx.x;
    const int g = tid >> 7;           // k-group 0..3 (wave-uniform: 2 waves per g)
    const int r = tid & 127;          // hidden index / gate-row within group
    const int b = blockIdx.x / 5;
    const int l = blockIdx.x % 5;

    int*   flagL  = (int*)(ws + FLAGL_OFF);
    int*   fcflag = (int*)(ws + FCFLAG_OFF) + b*64;
    float* fcout  = (float*)(ws + FCOUT_OFF) + b*2;
    float* ring   = (float*)(ws + RING_OFF);
    const float*   WhhT = (const float*)(ws + WHHT_OFF);
    const __half2* WP   = (const __half2*)(ws + WIHPK_OFF);

    int* upflag = flagL + (b*5 + (l > 0 ? l-1 : 0))*64;
    int* dnflag = flagL + (b*5 + (l < 4 ? l+1 : 4))*64;
    int* myflag = flagL + (b*5 + l)*64;

    // ---- register-resident weights ----
    // whh[j*32+kk] = W_hh[l][j*128+r][g*32+kk]  (fp32, recurrent path exact)
    float whh[128];
#pragma unroll
    for (int j = 0; j < 4; ++j)
#pragma unroll
        for (int kk = 0; kk < 32; ++kk)
            whh[j*32+kk] = WhhT[(l*128 + g*32 + kk)*512 + j*128 + r];

    // wih[j*16+m] = packed f16 pair of W_ih[l][j*128+r][g*32+2m, +1]   (layers 1..4)
    __half2 wih[64];
    if (l > 0) {
#pragma unroll
        for (int j = 0; j < 4; ++j)
#pragma unroll
            for (int m = 0; m < 16; ++m)
                wih[j*16+m] = WP[((l-1)*64 + g*16 + m)*512 + j*128 + r];
    }

    float bias[4] = {0.f,0.f,0.f,0.f};
    float wx[4]   = {0.f,0.f,0.f,0.f};
    float c = 0.f, b1r = 0.f;
    if (g == 0) {
#pragma unroll
        for (int j = 0; j < 4; ++j)
            bias[j] = bih[l*512 + j*128 + r] + bhh[l*512 + j*128 + r];
        if (l == 0) {
#pragma unroll
            for (int j = 0; j < 4; ++j) wx[j] = Wih0[j*128 + r];
        }
        if (l == 4) b1r = b1[r];
    }
    if (tid < 128) hown[tid] = 0.f;   // h(-1) = 0
    __syncthreads();

    const float* xb = x_in + b*512;

    for (int t = 0; t < 514; ++t) {
        // ---- phase 1: layer-0 input (FC feedback is the only real wait here) ----
        float xt = 0.f;
        if (l == 0) {
            if (t < 512) xt = xb[t];
            else {
                int need = t - 511, guard = 0;
                while (__hip_atomic_load(fcflag, __ATOMIC_ACQUIRE, AGENT) < need)
                    if (++guard > (1<<23)) break;       // safety valve: fail loud, not hang
                xt = __hip_atomic_load(&fcout[t-512], __ATOMIC_RELAXED, AGENT);
            }
        }

        // ---- phase 2: recurrent matvec (WG-local hown), fp32 weights in regs ----
        float acc[4] = {0.f,0.f,0.f,0.f};
        {
            const float4* h4 = (const float4*)(hown + g*32);
#pragma unroll
            for (int q = 0; q < 8; ++q) {
                float4 hq = h4[q];
#pragma unroll
                for (int j = 0; j < 4; ++j) {
                    acc[j] = fmaf(whh[j*32+4*q+0], hq.x, acc[j]);
                    acc[j] = fmaf(whh[j*32+4*q+1], hq.y, acc[j]);
                    acc[j] = fmaf(whh[j*32+4*q+2], hq.z, acc[j]);
                    acc[j] = fmaf(whh[j*32+4*q+3], hq.w, acc[j]);
                }
            }
        }

        // ---- acquire upstream h AFTER the hh matvec (spin overlapped with FMA above) ----
        if (l > 0) {
            int guard = 0;
            while (__hip_atomic_load(upflag, __ATOMIC_ACQUIRE, AGENT) < t+1)
                if (++guard > (1<<23)) break;
            if (tid < 128)
                hin[tid] = __hip_atomic_load(&ring[((b*4 + l-1)*RING + (t & (RING-1)))*128 + tid],
                                             __ATOMIC_RELAXED, AGENT);
        }
        __syncthreads();

        // ---- phase 3: input matvec (upstream h), f16 weights in regs ----
        if (l > 0) {
            const float4* h4 = (const float4*)(hin + g*32);
#pragma unroll
            for (int q = 0; q < 8; ++q) {
                float4 hq = h4[q];
#pragma unroll
                for (int j = 0; j < 4; ++j) {
                    __half2 wa = wih[j*16 + 2*q];
                    __half2 wb = wih[j*16 + 2*q + 1];
                    acc[j] = fmaf(__low2float(wa),  hq.x, acc[j]);
                    acc[j] = fmaf(__high2float(wa), hq.y, acc[j]);
                    acc[j] = fmaf(__low2float(wb),  hq.z, acc[j]);
                    acc[j] = fmaf(__high2float(wb), hq.w, acc[j]);
                }
            }
        }
        part4[g*128 + r] = make_float4(acc[0], acc[1], acc[2], acc[3]);
        __syncthreads();

        // ---- phase 4: combine partials + cell update (threads with g==0) ----
        if (g == 0) {
            float4 p0 = part4[r], p1 = part4[128+r], p2 = part4[256+r], p3 = part4[384+r];
            float gi = bias[0] + p0.x + p1.x + p2.x + p3.x + wx[0]*xt;
            float gf = bias[1] + p0.y + p1.y + p2.y + p3.y + wx[1]*xt;
            float gg = bias[2] + p0.z + p1.z + p2.z + p3.z + wx[2]*xt;
            float go = bias[3] + p0.w + p1.w + p2.w + p3.w + wx[3]*xt;
            float si = sigm(gi), sf = sigm(gf), gt = tanh_f(gg), so = sigm(go);
            c = fmaf(sf, c, si*gt);
            float h = so * tanh_f(c);
            hown[r] = h;
            if (l < 4) {
                if (t >= RING) {                       // ring backpressure (consumer lag < RING)
                    int guard = 0;
                    while (__hip_atomic_load(dnflag, __ATOMIC_RELAXED, AGENT) < t - (RING-1))
                        if (++guard > (1<<23)) break;
                }
                __hip_atomic_store(&ring[((b*4 + l)*RING + (t & (RING-1)))*128 + r], h,
                                   __ATOMIC_RELAXED, AGENT);
            }
        }
        __syncthreads();   // all waves drain vmcnt here -> ring stores globally visible

        // R1 FIX: every layer publishes progress (l==4's flag feeds layer-3 backpressure).
        if (tid == 0)
            __hip_atomic_store(myflag, t+1, __ATOMIC_RELEASE, AGENT);

        if (l == 4 && t >= 511) {
            // ---- FC head (3x total): z=relu(h); z2=relu(z@W1+b1); o=z2@W2+b2 ----
            const int iter = t - 511;
            if (g == 0) zbs[r] = fmaxf(hown[r], 0.f);
            __syncthreads();
            if (tid < 128) {
                float a = b1r;
#pragma unroll 8
                for (int k = 0; k < 128; ++k)
                    a = fmaf(zbs[k], W1[k*128 + tid], a);   // W1 from L2 (3x only)
                z2s[tid] = fmaxf(a, 0.f);
            }
            __syncthreads();
            if (tid < 16) {
                float o = b2[tid];
#pragma unroll 8
                for (int m = 0; m < 128; ++m)
                    o = fmaf(z2s[m], W2[m*16 + tid], o);
                if (iter == 2) {
                    out[b*18 + 2 + tid] = o;                // out2 full 16
                } else if (tid == 15) {
                    out[b*18 + iter] = o;                   // out_i[:, 15]
                    __hip_atomic_store(&fcout[iter], o, __ATOMIC_RELAXED, AGENT);
                    __hip_atomic_store(fcflag, iter+1, __ATOMIC_RELEASE, AGENT);
                }
            }
            __syncthreads();
        }
    }
}

extern "C" void kernel_launch(void* const* d_in, const int* in_sizes, int n_in,
                              void* d_out, int out_size, void* d_ws, size_t ws_size,
                              hipStream_t stream) {
    (void)in_sizes; (void)n_in; (void)out_size; (void)ws_size;  // needs ~4.5 MB of ws
    const float* x    = (const float*)d_in[0];
    // d_in[1] = future (18, hardcoded)
    const float* Wih0 = (const float*)d_in[2];
    const float* WihR = (const float*)d_in[3];
    const float* Whh  = (const float*)d_in[4];
    const float* bihp = (const float*)d_in[5];
    const float* bhhp = (const float*)d_in[6];
    const float* W1   = (const float*)d_in[7];
    const float* b1   = (const float*)d_in[8];
    const float* W2   = (const float*)d_in[9];
    const float* b2   = (const float*)d_in[10];
    char* ws = (char*)d_ws;

    lstm_init<<<256, 256, 0, stream>>>(WihR, Whh, ws);
    lstm_main<<<160, 512, 0, stream>>>(x, Wih0, bihp, bhhp, W1, b1, W2, b2,
                                       (float*)d_out, ws);
}

// Round 3
// 4541.132 us; speedup vs baseline: 1.4505x; 1.4505x over previous
//
#include <hip/hip_runtime.h>
#include <hip/hip_fp16.h>

// LSTMPredictor: B=32, T=512, H=128, L=5, IN=1, OUT=16, future=18 -> 3 autoregressive iters.
// ONE 514-step scan with carried (h,c); FC head at t=511,512,513; feedback via fcout/fcflag.
// 160 persistent WGs = 32 batch x 5 layers, 1-slot pipeline skew per layer.
//
// R3 overhaul (R2 ran 6.6ms at VALUBusy 2.6% -- coherence-op storm):
//  * ALL cross-WG traffic is RELAXED agent-scope atomics (sc1, coherence-point direct).
//    No ACQUIRE spins (no per-poll cache invalidate), no RELEASE flag stores (no buffer_wbl2).
//    Ordering: producer's __syncthreads drains vmcnt before tid0's flag store; consumer's
//    ring loads issue after the flag poll returns and bypass stale caches (sc1). Sound at ISA level.
//  * Chunked flag publish (every 4 steps; per-step for t>=504 tail) -> 4x less flag traffic.
//  * Early ring-load: if cached flag already covers t+1, issue ring load BEFORE the hh matvec
//    so its ~500cyc latency hides under the FMA block.
//  * Phase-2 packed float2 FMA -> v_pk_fma_f32 (full-rate dual fp32, exact) halves issue cycles.

typedef float f2 __attribute__((ext_vector_type(2)));

#define RING 16
#define FLAGL_OFF   0                 // int flagL[32][5], stride 64 ints
#define FCFLAG_OFF  (64*1024)         // int fcflag[32], stride 64 ints
#define FCOUT_OFF   (128*1024)        // float fcout[32][2]
#define RING_OFF    (256*1024)        // float ring[32][4][RING][128]  (1 MB)
#define WHHP_OFF    (2*1024*1024)     // f2 WhhP[5][64][512]           (1.25 MB)
#define WIHPK_OFF   (4*1024*1024)     // __half2 WihPk[4][64][512]     (0.5 MB)

#define AGENT __HIP_MEMORY_SCOPE_AGENT

__device__ __forceinline__ float sigm(float x)   { return 1.f / (1.f + __expf(-x)); }
__device__ __forceinline__ float tanh_f(float x) { return 2.f / (1.f + __expf(-2.f * x)) - 1.f; }

// ---------------- init: zero flags, pair-pack W_hh (fp32) and W_ih_rest (f16) ----------
__global__ void lstm_init(const float* __restrict__ WihR, const float* __restrict__ Whh,
                          char* __restrict__ ws)
{
    int idx = blockIdx.x * blockDim.x + threadIdx.x;
    int stride = gridDim.x * blockDim.x;

    int* wsi = (int*)ws;                       // zero [0, 256KB): flags + fcout
    for (int i = idx; i < 65536; i += stride) wsi[i] = 0;

    // WhhP[(l*64+km)*512+row] = {Whh[l][row][2km], Whh[l][row][2km+1]}
    f2* WP2 = (f2*)(ws + WHHP_OFF);
    for (int i = idx; i < 5*64*512; i += stride) {
        int row = i & 511, km = (i >> 9) & 63, l = i >> 15;
        const float* s = &Whh[(l*512 + row)*128 + 2*km];
        f2 v; v.x = s[0]; v.y = s[1];
        WP2[i] = v;
    }

    // WihPk[(li*64+km)*512+row] = pack_f16(WihR[li][row][2km], [2km+1])
    __half2* WH = (__half2*)(ws + WIHPK_OFF);
    for (int i = idx; i < 4*64*512; i += stride) {
        int row = i & 511, km = (i >> 9) & 63, li = i >> 15;
        const float* s = &WihR[(li*512 + row)*128 + 2*km];
        WH[i] = __floats2half2_rn(s[0], s[1]);
    }
}

// ---------------- main persistent pipeline kernel ----------------
__global__ void __launch_bounds__(512, 2)
lstm_main(const float* __restrict__ x_in, const float* __restrict__ Wih0,
          const float* __restrict__ bih,  const float* __restrict__ bhh,
          const float* __restrict__ W1,   const float* __restrict__ b1,
          const float* __restrict__ W2,   const float* __restrict__ b2,
          float* __restrict__ out, char* __restrict__ ws)
{
    __shared__ float4 part4[512];                 // per-(g,r) gate partials (i,f,g,o)
    __shared__ __align__(16) float hown[128];     // this layer's h(t-1)
    __shared__ __align__(16) float hin[128];      // upstream h(t)
    __shared__ float zbs[128];                    // FC: relu(h)
    __shared__ float z2s[128];                    // FC: relu(z@W1+b1)

    const int tid = threadIdx.x;
    const int g = tid >> 7;           // k-group 0..3
    const int r = tid & 127;          // hidden index / gate-row within group
    const int b = blockIdx.x / 5;
    const int l = blockIdx.x % 5;

    int*   flagL  = (int*)(ws + FLAGL_OFF);
    int*   fcflag = (int*)(ws + FCFLAG_OFF) + b*64;
    float* fcout  = (float*)(ws + FCOUT_OFF) + b*2;
    float* ring   = (float*)(ws + RING_OFF);
    const f2*      WP2 = (const f2*)(ws + WHHP_OFF);
    const __half2* WH  = (const __half2*)(ws + WIHPK_OFF);

    int* upflag = flagL + (b*5 + (l > 0 ? l-1 : 0))*64;
    int* dnflag = flagL + (b*5 + (l < 4 ? l+1 : 4))*64;
    int* myflag = flagL + (b*5 + l)*64;

    // ---- register-resident weights ----
    // whh2[j*16+m] = {W_hh[l][j*128+r][g*32+2m], [g*32+2m+1]}  (fp32, exact recurrent path)
    f2 whh2[64];
#pragma unroll
    for (int j = 0; j < 4; ++j)
#pragma unroll
        for (int m = 0; m < 16; ++m)
            whh2[j*16+m] = WP2[(l*64 + g*16 + m)*512 + j*128 + r];

    // wih[j*16+m] = f16 pair of W_ih[l][j*128+r][g*32+2m, +1]   (layers 1..4 only)
    __half2 wih[64];
    if (l > 0) {
#pragma unroll
        for (int j = 0; j < 4; ++j)
#pragma unroll
            for (int m = 0; m < 16; ++m)
                wih[j*16+m] = WH[((l-1)*64 + g*16 + m)*512 + j*128 + r];
    }

    float bias[4] = {0.f,0.f,0.f,0.f};
    float wx[4]   = {0.f,0.f,0.f,0.f};
    float c = 0.f, b1r = 0.f;
    if (g == 0) {
#pragma unroll
        for (int j = 0; j < 4; ++j)
            bias[j] = bih[l*512 + j*128 + r] + bhh[l*512 + j*128 + r];
        if (l == 0) {
#pragma unroll
            for (int j = 0; j < 4; ++j) wx[j] = Wih0[j*128 + r];
        }
        if (l == 4) b1r = b1[r];
    }
    if (tid < 128) hown[tid] = 0.f;   // h(-1) = 0
    __syncthreads();

    const float* xb = x_in + b*512;
    int lastup = 0;                   // cached upstream flag (avoids polling 3 of 4 steps)
    int lastdn = 0;                   // cached downstream flag (backpressure)

    for (int t = 0; t < 514; ++t) {
        const int slotL = ((b*4 + (l > 0 ? l-1 : 0))*RING + (t & (RING-1)))*128;

        // ---- phase 1: input acquire (early path overlaps ring-load with phase 2) ----
        float xt = 0.f, hinv = 0.f;
        bool have = false;
        if (l == 0) {
            if (t < 512) xt = xb[t];
            else {
                int need = t - 511, guard = 0;
                int f = __hip_atomic_load(fcflag, __ATOMIC_RELAXED, AGENT);
                while (f < need) {
                    if (++guard > (1<<23)) break;     // fail loud, never hang
                    f = __hip_atomic_load(fcflag, __ATOMIC_RELAXED, AGENT);
                }
                xt = __hip_atomic_load(&fcout[t-512], __ATOMIC_RELAXED, AGENT);
            }
        } else if (lastup >= t+1) {
            if (tid < 128)
                hinv = __hip_atomic_load(&ring[slotL + tid], __ATOMIC_RELAXED, AGENT);
            have = true;
        }

        // ---- phase 2: recurrent matvec, packed fp32 (v_pk_fma_f32), weights in regs ----
        f2 a2[4];
#pragma unroll
        for (int j = 0; j < 4; ++j) { a2[j].x = 0.f; a2[j].y = 0.f; }
        {
            const f2* h2 = (const f2*)(hown + g*32);
#pragma unroll
            for (int m = 0; m < 16; ++m) {
                f2 hh = h2[m];
#pragma unroll
                for (int j = 0; j < 4; ++j)
                    a2[j] = __builtin_elementwise_fma(whh2[j*16+m], hh, a2[j]);
            }
        }

        // ---- late path: spin (relaxed, no invalidates) then load ring ----
        if (l > 0 && !have) {
            int guard = 0;
            while (lastup < t+1) {
                if (++guard > (1<<23)) break;
                lastup = __hip_atomic_load(upflag, __ATOMIC_RELAXED, AGENT);
            }
            if (tid < 128)
                hinv = __hip_atomic_load(&ring[slotL + tid], __ATOMIC_RELAXED, AGENT);
        }
        if (l > 0 && tid < 128) hin[tid] = hinv;
        __syncthreads();

        // ---- phase 3: input matvec (upstream h), f16 weights in regs (v_fma_mix) ----
        float a3[4] = {0.f,0.f,0.f,0.f};
        if (l > 0) {
            const f2* h2 = (const f2*)(hin + g*32);
#pragma unroll
            for (int m = 0; m < 16; ++m) {
                f2 hh = h2[m];
#pragma unroll
                for (int j = 0; j < 4; ++j) {
                    __half2 w = wih[j*16+m];
                    a3[j] = fmaf(__low2float(w),  hh.x, a3[j]);
                    a3[j] = fmaf(__high2float(w), hh.y, a3[j]);
                }
            }
        }
        part4[g*128 + r] = make_float4(a2[0].x + a2[0].y + a3[0],
                                       a2[1].x + a2[1].y + a3[1],
                                       a2[2].x + a2[2].y + a3[2],
                                       a2[3].x + a2[3].y + a3[3]);
        __syncthreads();

        // ---- phase 4: combine partials + cell update (g==0 threads) ----
        if (g == 0) {
            float4 p0 = part4[r], p1 = part4[128+r], p2 = part4[256+r], p3 = part4[384+r];
            float gi = bias[0] + p0.x + p1.x + p2.x + p3.x + wx[0]*xt;
            float gf = bias[1] + p0.y + p1.y + p2.y + p3.y + wx[1]*xt;
            float gg = bias[2] + p0.z + p1.z + p2.z + p3.z + wx[2]*xt;
            float go = bias[3] + p0.w + p1.w + p2.w + p3.w + wx[3]*xt;
            float si = sigm(gi), sf = sigm(gf), gt = tanh_f(gg), so = sigm(go);
            c = fmaf(sf, c, si*gt);
            float h = so * tanh_f(c);
            hown[r] = h;
            if (l < 4) {
                if (t >= RING && lastdn < t - (RING-1)) {   // ring backpressure (rare)
                    int guard = 0;
                    while (lastdn < t - (RING-1)) {
                        if (++guard > (1<<23)) break;
                        lastdn = __hip_atomic_load(dnflag, __ATOMIC_RELAXED, AGENT);
                    }
                }
                __hip_atomic_store(&ring[((b*4 + l)*RING + (t & (RING-1)))*128 + r], h,
                                   __ATOMIC_RELAXED, AGENT);
            }
        }
        __syncthreads();   // all waves drain vmcnt -> ring stores at coherence point

        // chunked publish: every 4th step, per-step in the feedback tail
        if (tid == 0 && ((((t+1) & 3) == 0) || t >= 504))
            __hip_atomic_store(myflag, t+1, __ATOMIC_RELAXED, AGENT);

        if (l == 4 && t >= 511) {
            // ---- FC head (3x total): z=relu(h); z2=relu(z@W1+b1); o=z2@W2+b2 ----
            const int iter = t - 511;
            if (g == 0) zbs[r] = fmaxf(hown[r], 0.f);
            __syncthreads();
            if (tid < 128) {
                float a = b1r;
#pragma unroll 8
                for (int k = 0; k < 128; ++k)
                    a = fmaf(zbs[k], W1[k*128 + tid], a);   // W1 from L2 (3x only)
                z2s[tid] = fmaxf(a, 0.f);
            }
            __syncthreads();
            if (tid < 16) {
                float o = b2[tid];
#pragma unroll 8
                for (int m = 0; m < 128; ++m)
                    o = fmaf(z2s[m], W2[m*16 + tid], o);
                if (iter == 2) {
                    out[b*18 + 2 + tid] = o;                // out2 full 16
                } else if (tid == 15) {
                    out[b*18 + iter] = o;                   // out_i[:, 15]
                    __hip_atomic_store(&fcout[iter], o, __ATOMIC_RELAXED, AGENT);
                    __builtin_amdgcn_s_waitcnt(0);          // fcout at coherence point first
                    __hip_atomic_store(fcflag, iter+1, __ATOMIC_RELAXED, AGENT);
                }
            }
            __syncthreads();
        }
    }
}

extern "C" void kernel_launch(void* const* d_in, const int* in_sizes, int n_in,
                              void* d_out, int out_size, void* d_ws, size_t ws_size,
                              hipStream_t stream) {
    (void)in_sizes; (void)n_in; (void)out_size; (void)ws_size;  // needs ~4.5 MB of ws
    const float* x    = (const float*)d_in[0];
    // d_in[1] = future (18, hardcoded)
    const float* Wih0 = (const float*)d_in[2];
    const float* WihR = (const float*)d_in[3];
    const float* Whh  = (const float*)d_in[4];
    const float* bihp = (const float*)d_in[5];
    const float* bhhp = (const float*)d_in[6];
    const float* W1   = (const float*)d_in[7];
    const float* b1   = (const float*)d_in[8];
    const float* W2   = (const float*)d_in[9];
    const float* b2   = (const float*)d_in[10];
    char* ws = (char*)d_ws;

    lstm_init<<<256, 256, 0, stream>>>(WihR, Whh, ws);
    lstm_main<<<160, 512, 0, stream>>>(x, Wih0, bihp, bhhp, W1, b1, W2, b2,
                                       (float*)d_out, ws);
}

// Round 4
// 2738.941 us; speedup vs baseline: 2.4049x; 1.6580x over previous
//
#include <hip/hip_runtime.h>
#include <hip/hip_fp16.h>

// LSTMPredictor: B=32, T=512, H=128, L=5, IN=1, OUT=16, future=18 -> 3 autoregressive iters.
// ONE 514-step scan with carried (h,c); FC head at t=511,512,513; feedback via fcout/fcflag.
// 160 persistent WGs = 32 batch x 5 layers.
//
// R4 (R3 = 4.5ms, VALUBusy 4%: per-step sc1 round trips + per-barrier vmcnt drains):
//  * 4-step CHUNKED h transport: 1 sc1 store + 1 poll + 1 sc1 load per chunk (was ~6 ops/step).
//    Producer's chunk store is drained a full chunk later (fully hidden).
//  * lgkm-only barriers (asm) in the hot loop; explicit vmcnt drains only at chunk boundaries.
//  * In-wave reduction: threads (row=tid>>2, kslice=tid&3); 2x shfl_xor replaces LDS part4
//    round-trip -> ONE barrier per mid-chunk step.
//  * Tail (t>=500) switches to per-step transport for the feedback steps.

typedef float f2 __attribute__((ext_vector_type(2)));

#define RING 16
#define TAIL 500                      // chunk-aligned switch to per-step mode
#define GUARD (1<<16)

#define FLAGL_OFF   0                 // int flagL[32][5], stride 64 ints
#define FCFLAG_OFF  (64*1024)         // int fcflag[32], stride 64 ints
#define FCOUT_OFF   (128*1024)        // float fcout[32][2]
#define RING_OFF    (256*1024)        // float ring[32][4][RING][128]  (1 MB)
#define WHHP_OFF    (2*1024*1024)     // f2 WhhP[5][64][512]           (1.25 MB)
#define WIHPK_OFF   (4*1024*1024)     // __half2 WihPk[4][64][512]     (0.5 MB)

#define AGENT __HIP_MEMORY_SCOPE_AGENT
#define LD(p)    __hip_atomic_load((p),  __ATOMIC_RELAXED, AGENT)
#define ST(p,v)  __hip_atomic_store((p), (v), __ATOMIC_RELAXED, AGENT)

__device__ __forceinline__ void bar_lgkm() {   // barrier w/o vmcnt drain (LDS hazards only)
    asm volatile("s_waitcnt lgkmcnt(0)\n\ts_barrier" ::: "memory");
}
__device__ __forceinline__ void drain_vm() {   // drain own wave's global ops
    asm volatile("s_waitcnt vmcnt(0)" ::: "memory");
}

__device__ __forceinline__ float sigm(float x)   { return 1.f / (1.f + __expf(-x)); }
__device__ __forceinline__ float tanh_f(float x) { return 2.f / (1.f + __expf(-2.f * x)) - 1.f; }

// ---------------- init: zero flags, pair-pack W_hh (fp32) and W_ih_rest (f16) ----------
__global__ void lstm_init(const float* __restrict__ WihR, const float* __restrict__ Whh,
                          char* __restrict__ ws)
{
    int idx = blockIdx.x * blockDim.x + threadIdx.x;
    int stride = gridDim.x * blockDim.x;

    int* wsi = (int*)ws;                       // zero [0, 256KB): flags + fcout
    for (int i = idx; i < 65536; i += stride) wsi[i] = 0;

    f2* WP2 = (f2*)(ws + WHHP_OFF);            // WhhP[(l*64+km)*512+row] = Whh[l][row][2km..+1]
    for (int i = idx; i < 5*64*512; i += stride) {
        int row = i & 511, km = (i >> 9) & 63, l = i >> 15;
        const float* s = &Whh[(l*512 + row)*128 + 2*km];
        f2 v; v.x = s[0]; v.y = s[1];
        WP2[i] = v;
    }

    __half2* WH = (__half2*)(ws + WIHPK_OFF);  // WihPk[(li*64+km)*512+row]
    for (int i = idx; i < 4*64*512; i += stride) {
        int row = i & 511, km = (i >> 9) & 63, li = i >> 15;
        const float* s = &WihR[(li*512 + row)*128 + 2*km];
        WH[i] = __floats2half2_rn(s[0], s[1]);
    }
}

// ---------------- main persistent pipeline kernel ----------------
__global__ void __launch_bounds__(512, 2)
lstm_main(const float* __restrict__ x_in, const float* __restrict__ Wih0,
          const float* __restrict__ bih,  const float* __restrict__ bhh,
          const float* __restrict__ W1,   const float* __restrict__ b1,
          const float* __restrict__ W2,   const float* __restrict__ b2,
          float* __restrict__ out, char* __restrict__ ws)
{
    __shared__ __align__(16) float hown[128];   // this layer's h(t-1)
    __shared__ __align__(16) float hc_in[512];  // incoming h chunk (4 slots x 128)
    __shared__ __align__(16) float hc_out[512]; // outgoing h chunk
    __shared__ float zbs[128];                  // FC: relu(h)
    __shared__ float z2s[128];                  // FC: relu(z@W1+b1)

    const int tid = threadIdx.x;
    const int r  = tid >> 2;          // hidden row 0..127
    const int kg = tid & 3;           // k-slice 0..3 (adjacent LANES -> shfl reduce)
    const int b = blockIdx.x / 5;
    const int l = blockIdx.x % 5;
    const bool isProd = (l < 4);
    const bool isCons = (l > 0);

    int*   flagL  = (int*)(ws + FLAGL_OFF);
    int*   fcflag = (int*)(ws + FCFLAG_OFF) + b*64;
    float* fcout  = (float*)(ws + FCOUT_OFF) + b*2;
    float* ringAll= (float*)(ws + RING_OFF);
    const f2*      WP2 = (const f2*)(ws + WHHP_OFF);
    const __half2* WH  = (const __half2*)(ws + WIHPK_OFF);

    int* upflag = flagL + (b*5 + (l > 0 ? l-1 : 0))*64;
    int* dnflag = flagL + (b*5 + (l < 4 ? l+1 : 4))*64;
    int* myflag = flagL + (b*5 + l)*64;
    float* upRing = ringAll + (b*4 + (l > 0 ? l-1 : 0))*RING*128;
    float* myRing = ringAll + (b*4 + (l < 4 ? l   : 0))*RING*128;

    // ---- register-resident weights ----
    // whh2[j*16+m] = {W_hh[l][j*128+r][kg*32+2m], [+1]}  (fp32, exact recurrent path)
    f2 whh2[64];
#pragma unroll
    for (int j = 0; j < 4; ++j)
#pragma unroll
        for (int m = 0; m < 16; ++m)
            whh2[j*16+m] = WP2[(l*64 + kg*16 + m)*512 + j*128 + r];

    __half2 wih[64];                  // f16 pairs, layers 1..4 only
    if (isCons) {
#pragma unroll
        for (int j = 0; j < 4; ++j)
#pragma unroll
            for (int m = 0; m < 16; ++m)
                wih[j*16+m] = WH[((l-1)*64 + kg*16 + m)*512 + j*128 + r];
    }

    float bias[4] = {0.f,0.f,0.f,0.f};
    float wx[4]   = {0.f,0.f,0.f,0.f};
    float c = 0.f;
    if (kg == 0) {
#pragma unroll
        for (int j = 0; j < 4; ++j)
            bias[j] = bih[l*512 + j*128 + r] + bhh[l*512 + j*128 + r];
        if (l == 0) {
#pragma unroll
            for (int j = 0; j < 4; ++j) wx[j] = Wih0[j*128 + r];
        }
    }
    if (tid < 128) hown[tid] = 0.f;   // h(-1) = 0
    __syncthreads();

    const float* xb = x_in + b*512;
    int lastup = 0, lastdn = 0;

    for (int t = 0; t < 514; ++t) {
        const int sub = t & 3;

        // ================= transport: chunk start / tail per-step =================
        if (t < TAIL) {
            if (sub == 0) {
                float hv = 0.f;
                if (isCons) {
                    int guard = 0;                      // need producer chunk [t..t+3] done
                    while (lastup < t+4) {
                        if (++guard > GUARD) break;     // fail loud, never hang
                        lastup = LD(upflag);
                    }
                    hv = LD(&upRing[(t & (RING-1))*128 + tid]);   // 4 slots x 128 = 2KB
                }
                drain_vm();            // drains own chunk load AND last chunk's ring store
                if (isCons) hc_in[tid] = hv;
                bar_lgkm();            // hc_in visible; all waves' stores drained
                if (t > 0 && tid == 0) ST(myflag, t);   // publish previous chunk
            }
        } else {
            // tail: per-step transport (feedback region)
            if (isCons) {
                int guard = 0;
                while (lastup < t+1) {
                    if (++guard > GUARD) break;
                    lastup = LD(upflag);
                }
                float hv = 0.f;
                if (tid < 128) hv = LD(&upRing[(t & (RING-1))*128 + tid]);
                drain_vm();
                if (tid < 128) hc_in[sub*128 + tid] = hv;
            } else {
                drain_vm();
            }
            bar_lgkm();
        }

        // ---- layer-0 input ----
        float xt = 0.f;
        if (l == 0) {
            if (t < 512) xt = xb[t];
            else {
                int need = t - 511, guard = 0;
                int f = LD(fcflag);
                while (f < need) {
                    if (++guard > GUARD) break;
                    f = LD(fcflag);
                }
                xt = LD(&fcout[t-512]);
            }
        }

        // ================= fused matvec: recurrent (fp32 pk-fma) + input (f16 mix) ====
        f2 a2[4];
#pragma unroll
        for (int j = 0; j < 4; ++j) { a2[j].x = 0.f; a2[j].y = 0.f; }
        {
            const f2* h2 = (const f2*)(hown + kg*32);
#pragma unroll
            for (int m = 0; m < 16; ++m) {
                f2 hh = h2[m];
#pragma unroll
                for (int j = 0; j < 4; ++j)
                    a2[j] = __builtin_elementwise_fma(whh2[j*16+m], hh, a2[j]);
            }
        }
        float a[4];
#pragma unroll
        for (int j = 0; j < 4; ++j) a[j] = a2[j].x + a2[j].y;
        if (isCons) {
            const f2* h2 = (const f2*)(hc_in + sub*128 + kg*32);
#pragma unroll
            for (int m = 0; m < 16; ++m) {
                f2 hh = h2[m];
#pragma unroll
                for (int j = 0; j < 4; ++j) {
                    __half2 w = wih[j*16+m];
                    a[j] = fmaf(__low2float(w),  hh.x, a[j]);
                    a[j] = fmaf(__high2float(w), hh.y, a[j]);
                }
            }
        }

        // ---- in-wave reduce across kg (lanes xor 1,2) ----
#pragma unroll
        for (int j = 0; j < 4; ++j) {
            a[j] += __shfl_xor(a[j], 1, 64);
            a[j] += __shfl_xor(a[j], 2, 64);
        }

        // ---- cell update on kg==0 lanes ----
        if (kg == 0) {
            float gi = bias[0] + a[0] + wx[0]*xt;
            float gf = bias[1] + a[1] + wx[1]*xt;
            float gg = bias[2] + a[2] + wx[2]*xt;
            float go = bias[3] + a[3] + wx[3]*xt;
            float si = sigm(gi), sf = sigm(gf), gt = tanh_f(gg), so = sigm(go);
            c = fmaf(sf, c, si*gt);
            float h = so * tanh_f(c);
            hown[r] = h;
            if (isProd) {
                if (t < TAIL) hc_out[sub*128 + r] = h;
                else          ST(&myRing[(t & (RING-1))*128 + r], h);
            }
        }
        bar_lgkm();    // hown (+hc_out) visible for next step / chunk store

        // ================= transport: chunk end / tail publish =================
        if (t < TAIL) {
            if (sub == 3 && isProd) {
                // backpressure: about to overwrite slots of steps t-19..t-16 next chunk;
                // also ensures consumer lag < RING before this store lands.
                if (t >= RING && lastdn < t-15) {
                    int guard = 0;
                    while (lastdn < t-15) {
                        if (++guard > GUARD) break;
                        lastdn = LD(dnflag);
                    }
                }
                ST(&myRing[((t-3) & (RING-1))*128 + tid], hc_out[tid]);  // 2KB, no drain
            }
        } else {
            drain_vm();                 // tail: drain h store (and any chunk-store leftovers)
            bar_lgkm();
            if (tid == 0) ST(myflag, t+1);
        }

        // ================= FC head (l==4, t>=511; 3x total) =================
        if (l == 4 && t >= 511) {
            const int iter = t - 511;
            if (tid < 128) zbs[tid] = fmaxf(hown[tid], 0.f);
            bar_lgkm();
            if (tid < 128) {
                float acc = b1[tid];
#pragma unroll 8
                for (int k = 0; k < 128; ++k)
                    acc = fmaf(zbs[k], W1[k*128 + tid], acc);   // W1 from L2 (3x only)
                z2s[tid] = fmaxf(acc, 0.f);
            }
            bar_lgkm();
            if (tid < 16) {
                float o = b2[tid];
#pragma unroll 8
                for (int m = 0; m < 128; ++m)
                    o = fmaf(z2s[m], W2[m*16 + tid], o);
                if (iter == 2) {
                    out[b*18 + 2 + tid] = o;                // out2 full 16
                } else if (tid == 15) {
                    out[b*18 + iter] = o;                   // out_i[:, 15]
                    ST(&fcout[iter], o);
                    drain_vm();                             // fcout visible first
                    ST(fcflag, iter+1);
                }
            }
            bar_lgkm();
        }
    }
}

extern "C" void kernel_launch(void* const* d_in, const int* in_sizes, int n_in,
                              void* d_out, int out_size, void* d_ws, size_t ws_size,
                              hipStream_t stream) {
    (void)in_sizes; (void)n_in; (void)out_size; (void)ws_size;  // needs ~4.5 MB of ws
    const float* x    = (const float*)d_in[0];
    // d_in[1] = future (18, hardcoded)
    const float* Wih0 = (const float*)d_in[2];
    const float* WihR = (const float*)d_in[3];
    const float* Whh  = (const float*)d_in[4];
    const float* bihp = (const float*)d_in[5];
    const float* bhhp = (const float*)d_in[6];
    const float* W1   = (const float*)d_in[7];
    const float* b1   = (const float*)d_in[8];
    const float* W2   = (const float*)d_in[9];
    const float* b2   = (const float*)d_in[10];
    char* ws = (char*)d_ws;

    lstm_init<<<256, 256, 0, stream>>>(WihR, Whh, ws);
    lstm_main<<<160, 512, 0, stream>>>(x, Wih0, bihp, bhhp, W1, b1, W2, b2,
                                       (float*)d_out, ws);
}

// Round 5
// 2734.180 us; speedup vs baseline: 2.4091x; 1.0017x over previous
//
#include <hip/hip_runtime.h>
#include <hip/hip_fp16.h>

// LSTMPredictor: B=32, T=512, H=128, L=5, IN=1, OUT=16, future=18 -> 3 autoregressive iters.
// ONE 514-step scan with carried (h,c); FC head at t=511,512,513; feedback via fcout/fcflag.
// 160 persistent WGs = 32 batch x 5 layers; 4-step chunked sc1 h-transport (R4 protocol).
//
// R5: THE register fix. All prior rounds showed VGPR_Count=128 while the design needs ~225
// (whh2=128 + wih=64 + working) -> weight arrays were SPILLED TO SCRATCH; phases 2-3 were
// streaming ~384KB/WG-step from L2/HBM, not registers. Cause: __launch_bounds__(512,2)'s
// 2nd arg acted as min-blocks-per-CU (CUDA-style) -> 4 waves/EU -> 128-reg cap.
// Fix: __launch_bounds__(512) + amdgpu_waves_per_eu(1,2) -> 256-reg budget, 1 WG/CU.
// Everything else identical to R4 (attributable delta).

typedef float f2 __attribute__((ext_vector_type(2)));

#define RING 16
#define TAIL 500                      // chunk-aligned switch to per-step mode
#define GUARD (1<<16)

#define FLAGL_OFF   0                 // int flagL[32][5], stride 64 ints
#define FCFLAG_OFF  (64*1024)         // int fcflag[32], stride 64 ints
#define FCOUT_OFF   (128*1024)        // float fcout[32][2]
#define RING_OFF    (256*1024)        // float ring[32][4][RING][128]  (1 MB)
#define WHHP_OFF    (2*1024*1024)     // f2 WhhP[5][64][512]           (1.25 MB)
#define WIHPK_OFF   (4*1024*1024)     // __half2 WihPk[4][64][512]     (0.5 MB)

#define AGENT __HIP_MEMORY_SCOPE_AGENT
#define LD(p)    __hip_atomic_load((p),  __ATOMIC_RELAXED, AGENT)
#define ST(p,v)  __hip_atomic_store((p), (v), __ATOMIC_RELAXED, AGENT)

__device__ __forceinline__ void bar_lgkm() {   // barrier w/o vmcnt drain (LDS hazards only)
    asm volatile("s_waitcnt lgkmcnt(0)\n\ts_barrier" ::: "memory");
}
__device__ __forceinline__ void drain_vm() {   // drain own wave's global ops
    asm volatile("s_waitcnt vmcnt(0)" ::: "memory");
}

__device__ __forceinline__ float sigm(float x)   { return 1.f / (1.f + __expf(-x)); }
__device__ __forceinline__ float tanh_f(float x) { return 2.f / (1.f + __expf(-2.f * x)) - 1.f; }

// ---------------- init: zero flags, pair-pack W_hh (fp32) and W_ih_rest (f16) ----------
__global__ void lstm_init(const float* __restrict__ WihR, const float* __restrict__ Whh,
                          char* __restrict__ ws)
{
    int idx = blockIdx.x * blockDim.x + threadIdx.x;
    int stride = gridDim.x * blockDim.x;

    int* wsi = (int*)ws;                       // zero [0, 256KB): flags + fcout
    for (int i = idx; i < 65536; i += stride) wsi[i] = 0;

    f2* WP2 = (f2*)(ws + WHHP_OFF);            // WhhP[(l*64+km)*512+row] = Whh[l][row][2km..+1]
    for (int i = idx; i < 5*64*512; i += stride) {
        int row = i & 511, km = (i >> 9) & 63, l = i >> 15;
        const float* s = &Whh[(l*512 + row)*128 + 2*km];
        f2 v; v.x = s[0]; v.y = s[1];
        WP2[i] = v;
    }

    __half2* WH = (__half2*)(ws + WIHPK_OFF);  // WihPk[(li*64+km)*512+row]
    for (int i = idx; i < 4*64*512; i += stride) {
        int row = i & 511, km = (i >> 9) & 63, li = i >> 15;
        const float* s = &WihR[(li*512 + row)*128 + 2*km];
        WH[i] = __floats2half2_rn(s[0], s[1]);
    }
}

// ---------------- main persistent pipeline kernel ----------------
__global__ void __launch_bounds__(512)
__attribute__((amdgpu_waves_per_eu(1, 2)))
lstm_main(const float* __restrict__ x_in, const float* __restrict__ Wih0,
          const float* __restrict__ bih,  const float* __restrict__ bhh,
          const float* __restrict__ W1,   const float* __restrict__ b1,
          const float* __restrict__ W2,   const float* __restrict__ b2,
          float* __restrict__ out, char* __restrict__ ws)
{
    __shared__ __align__(16) float hown[128];   // this layer's h(t-1)
    __shared__ __align__(16) float hc_in[512];  // incoming h chunk (4 slots x 128)
    __shared__ __align__(16) float hc_out[512]; // outgoing h chunk
    __shared__ float zbs[128];                  // FC: relu(h)
    __shared__ float z2s[128];                  // FC: relu(z@W1+b1)

    const int tid = threadIdx.x;
    const int r  = tid >> 2;          // hidden row 0..127
    const int kg = tid & 3;           // k-slice 0..3 (adjacent LANES -> shfl reduce)
    const int b = blockIdx.x / 5;
    const int l = blockIdx.x % 5;
    const bool isProd = (l < 4);
    const bool isCons = (l > 0);

    int*   flagL  = (int*)(ws + FLAGL_OFF);
    int*   fcflag = (int*)(ws + FCFLAG_OFF) + b*64;
    float* fcout  = (float*)(ws + FCOUT_OFF) + b*2;
    float* ringAll= (float*)(ws + RING_OFF);
    const f2*      WP2 = (const f2*)(ws + WHHP_OFF);
    const __half2* WH  = (const __half2*)(ws + WIHPK_OFF);

    int* upflag = flagL + (b*5 + (l > 0 ? l-1 : 0))*64;
    int* dnflag = flagL + (b*5 + (l < 4 ? l+1 : 4))*64;
    int* myflag = flagL + (b*5 + l)*64;
    float* upRing = ringAll + (b*4 + (l > 0 ? l-1 : 0))*RING*128;
    float* myRing = ringAll + (b*4 + (l < 4 ? l   : 0))*RING*128;

    // ---- register-resident weights (R5: actually resident now) ----
    // whh2[j*16+m] = {W_hh[l][j*128+r][kg*32+2m], [+1]}  (fp32, exact recurrent path)
    f2 whh2[64];
#pragma unroll
    for (int j = 0; j < 4; ++j)
#pragma unroll
        for (int m = 0; m < 16; ++m)
            whh2[j*16+m] = WP2[(l*64 + kg*16 + m)*512 + j*128 + r];

    __half2 wih[64];                  // f16 pairs, layers 1..4 only
    if (isCons) {
#pragma unroll
        for (int j = 0; j < 4; ++j)
#pragma unroll
            for (int m = 0; m < 16; ++m)
                wih[j*16+m] = WH[((l-1)*64 + kg*16 + m)*512 + j*128 + r];
    }

    float bias[4] = {0.f,0.f,0.f,0.f};
    float wx[4]   = {0.f,0.f,0.f,0.f};
    float c = 0.f;
    if (kg == 0) {
#pragma unroll
        for (int j = 0; j < 4; ++j)
            bias[j] = bih[l*512 + j*128 + r] + bhh[l*512 + j*128 + r];
        if (l == 0) {
#pragma unroll
            for (int j = 0; j < 4; ++j) wx[j] = Wih0[j*128 + r];
        }
    }
    if (tid < 128) hown[tid] = 0.f;   // h(-1) = 0
    __syncthreads();

    const float* xb = x_in + b*512;
    int lastup = 0, lastdn = 0;

    for (int t = 0; t < 514; ++t) {
        const int sub = t & 3;

        // ================= transport: chunk start / tail per-step =================
        if (t < TAIL) {
            if (sub == 0) {
                float hv = 0.f;
                if (isCons) {
                    int guard = 0;                      // need producer chunk [t..t+3] done
                    while (lastup < t+4) {
                        if (++guard > GUARD) break;     // fail loud, never hang
                        lastup = LD(upflag);
                    }
                    hv = LD(&upRing[(t & (RING-1))*128 + tid]);   // 4 slots x 128 = 2KB
                }
                drain_vm();            // drains own chunk load AND last chunk's ring store
                if (isCons) hc_in[tid] = hv;
                bar_lgkm();            // hc_in visible; all waves' stores drained
                if (t > 0 && tid == 0) ST(myflag, t);   // publish previous chunk
            }
        } else {
            // tail: per-step transport (feedback region)
            if (isCons) {
                int guard = 0;
                while (lastup < t+1) {
                    if (++guard > GUARD) break;
                    lastup = LD(upflag);
                }
                float hv = 0.f;
                if (tid < 128) hv = LD(&upRing[(t & (RING-1))*128 + tid]);
                drain_vm();
                if (tid < 128) hc_in[sub*128 + tid] = hv;
            } else {
                drain_vm();
            }
            bar_lgkm();
        }

        // ---- layer-0 input ----
        float xt = 0.f;
        if (l == 0) {
            if (t < 512) xt = xb[t];
            else {
                int need = t - 511, guard = 0;
                int f = LD(fcflag);
                while (f < need) {
                    if (++guard > GUARD) break;
                    f = LD(fcflag);
                }
                xt = LD(&fcout[t-512]);
            }
        }

        // ================= fused matvec: recurrent (fp32 pk-fma) + input (f16) ====
        f2 a2[4];
#pragma unroll
        for (int j = 0; j < 4; ++j) { a2[j].x = 0.f; a2[j].y = 0.f; }
        {
            const f2* h2 = (const f2*)(hown + kg*32);
#pragma unroll
            for (int m = 0; m < 16; ++m) {
                f2 hh = h2[m];
#pragma unroll
                for (int j = 0; j < 4; ++j)
                    a2[j] = __builtin_elementwise_fma(whh2[j*16+m], hh, a2[j]);
            }
        }
        float a[4];
#pragma unroll
        for (int j = 0; j < 4; ++j) a[j] = a2[j].x + a2[j].y;
        if (isCons) {
            const f2* h2 = (const f2*)(hc_in + sub*128 + kg*32);
#pragma unroll
            for (int m = 0; m < 16; ++m) {
                f2 hh = h2[m];
#pragma unroll
                for (int j = 0; j < 4; ++j) {
                    __half2 w = wih[j*16+m];
                    a[j] = fmaf(__low2float(w),  hh.x, a[j]);
                    a[j] = fmaf(__high2float(w), hh.y, a[j]);
                }
            }
        }

        // ---- in-wave reduce across kg (lanes xor 1,2) ----
#pragma unroll
        for (int j = 0; j < 4; ++j) {
            a[j] += __shfl_xor(a[j], 1, 64);
            a[j] += __shfl_xor(a[j], 2, 64);
        }

        // ---- cell update on kg==0 lanes ----
        if (kg == 0) {
            float gi = bias[0] + a[0] + wx[0]*xt;
            float gf = bias[1] + a[1] + wx[1]*xt;
            float gg = bias[2] + a[2] + wx[2]*xt;
            float go = bias[3] + a[3] + wx[3]*xt;
            float si = sigm(gi), sf = sigm(gf), gt = tanh_f(gg), so = sigm(go);
            c = fmaf(sf, c, si*gt);
            float h = so * tanh_f(c);
            hown[r] = h;
            if (isProd) {
                if (t < TAIL) hc_out[sub*128 + r] = h;
                else          ST(&myRing[(t & (RING-1))*128 + r], h);
            }
        }
        bar_lgkm();    // hown (+hc_out) visible for next step / chunk store

        // ================= transport: chunk end / tail publish =================
        if (t < TAIL) {
            if (sub == 3 && isProd) {
                // backpressure: consumer must have started chunk t-15 before we overwrite
                if (t >= RING && lastdn < t-15) {
                    int guard = 0;
                    while (lastdn < t-15) {
                        if (++guard > GUARD) break;
                        lastdn = LD(dnflag);
                    }
                }
                ST(&myRing[((t-3) & (RING-1))*128 + tid], hc_out[tid]);  // 2KB, no drain
            }
        } else {
            drain_vm();                 // tail: drain h store (and any chunk-store leftovers)
            bar_lgkm();
            if (tid == 0) ST(myflag, t+1);
        }

        // ================= FC head (l==4, t>=511; 3x total) =================
        if (l == 4 && t >= 511) {
            const int iter = t - 511;
            if (tid < 128) zbs[tid] = fmaxf(hown[tid], 0.f);
            bar_lgkm();
            if (tid < 128) {
                float acc = b1[tid];
#pragma unroll 8
                for (int k = 0; k < 128; ++k)
                    acc = fmaf(zbs[k], W1[k*128 + tid], acc);   // W1 from L2 (3x only)
                z2s[tid] = fmaxf(acc, 0.f);
            }
            bar_lgkm();
            if (tid < 16) {
                float o = b2[tid];
#pragma unroll 8
                for (int m = 0; m < 128; ++m)
                    o = fmaf(z2s[m], W2[m*16 + tid], o);
                if (iter == 2) {
                    out[b*18 + 2 + tid] = o;                // out2 full 16
                } else if (tid == 15) {
                    out[b*18 + iter] = o;                   // out_i[:, 15]
                    ST(&fcout[iter], o);
                    drain_vm();                             // fcout visible first
                    ST(fcflag, iter+1);
                }
            }
            bar_lgkm();
        }
    }
}

extern "C" void kernel_launch(void* const* d_in, const int* in_sizes, int n_in,
                              void* d_out, int out_size, void* d_ws, size_t ws_size,
                              hipStream_t stream) {
    (void)in_sizes; (void)n_in; (void)out_size; (void)ws_size;  // needs ~4.5 MB of ws
    const float* x    = (const float*)d_in[0];
    // d_in[1] = future (18, hardcoded)
    const float* Wih0 = (const float*)d_in[2];
    const float* WihR = (const float*)d_in[3];
    const float* Whh  = (const float*)d_in[4];
    const float* bihp = (const float*)d_in[5];
    const float* bhhp = (const float*)d_in[6];
    const float* W1   = (const float*)d_in[7];
    const float* b1   = (const float*)d_in[8];
    const float* W2   = (const float*)d_in[9];
    const float* b2   = (const float*)d_in[10];
    char* ws = (char*)d_ws;

    lstm_init<<<256, 256, 0, stream>>>(WihR, Whh, ws);
    lstm_main<<<160, 512, 0, stream>>>(x, Wih0, bihp, bhhp, W1, b1, W2, b2,
                                       (float*)d_out, ws);
}